// Round 1
// baseline (1832.280 us; speedup 1.0000x reference)
//
#include <hip/hip_runtime.h>

#define NB 8192
#define NT 24

__device__ __forceinline__ float rcp_fast(float x) { return __builtin_amdgcn_rcpf(x); }
__device__ __forceinline__ float sigmoid_f(float x) { return rcp_fast(1.f + __expf(-x)); }
__device__ __forceinline__ float tanh_f(float x) { return 1.f - 2.f * rcp_fast(1.f + __expf(2.f * x)); }

// Full sum across the 16 contiguous lanes of a group (groups aligned to 16).
// Stages: quad xor1, quad xor2, row_half_mirror, row_mirror -> all 16 lanes hold the sum.
__device__ __forceinline__ float dpp16_sum(float x) {
  int v;
  v = __builtin_amdgcn_update_dpp(0, __float_as_int(x), 0xB1, 0xF, 0xF, true);  // quad_perm(1,0,3,2)
  x += __int_as_float(v);
  v = __builtin_amdgcn_update_dpp(0, __float_as_int(x), 0x4E, 0xF, 0xF, true);  // quad_perm(2,3,0,1)
  x += __int_as_float(v);
  v = __builtin_amdgcn_update_dpp(0, __float_as_int(x), 0x141, 0xF, 0xF, true); // ROW_HALF_MIRROR
  x += __int_as_float(v);
  v = __builtin_amdgcn_update_dpp(0, __float_as_int(x), 0x140, 0xF, 0xF, true); // ROW_MIRROR
  x += __int_as_float(v);
  return x;
}

// 6-row (r,z,n for j0 and j1) x 4-col FMA block against a padded [rows][36] LDS matrix.
#define GATE6(WS, BV0, BV1, BV2, BV3, COFF)                          \
  do {                                                               \
    const float4 wr0 = *(const float4*)&WS[(j0) * 36 + (COFF)];      \
    const float4 wz0 = *(const float4*)&WS[(32 + j0) * 36 + (COFF)]; \
    const float4 wn0 = *(const float4*)&WS[(64 + j0) * 36 + (COFF)]; \
    const float4 wr1 = *(const float4*)&WS[(j1) * 36 + (COFF)];      \
    const float4 wz1 = *(const float4*)&WS[(32 + j1) * 36 + (COFF)]; \
    const float4 wn1 = *(const float4*)&WS[(64 + j1) * 36 + (COFF)]; \
    gr0 += BV0 * wr0.x + BV1 * wr0.y + BV2 * wr0.z + BV3 * wr0.w;    \
    gz0 += BV0 * wz0.x + BV1 * wz0.y + BV2 * wz0.z + BV3 * wz0.w;    \
    gn0 += BV0 * wn0.x + BV1 * wn0.y + BV2 * wn0.z + BV3 * wn0.w;    \
    gr1 += BV0 * wr1.x + BV1 * wr1.y + BV2 * wr1.z + BV3 * wr1.w;    \
    gz1 += BV0 * wz1.x + BV1 * wz1.y + BV2 * wz1.z + BV3 * wz1.w;    \
    gn1 += BV0 * wn1.x + BV1 * wn1.y + BV2 * wn1.z + BV3 * wn1.w;    \
  } while (0)

__global__ __launch_bounds__(256, 2) void darnn_kernel(
    const float* __restrict__ x, const float* __restrict__ h0_enc, const float* __restrict__ h0_dec,
    const float* __restrict__ attn1_w, const float* __restrict__ attn1_b,
    const float* __restrict__ attn2_w, const float* __restrict__ attn2_b,
    const float* __restrict__ attn3_w, const float* __restrict__ attn3_b,
    const float* __restrict__ enc_wih, const float* __restrict__ enc_whh,
    const float* __restrict__ enc_bih, const float* __restrict__ enc_bhh,
    const float* __restrict__ l1_w, const float* __restrict__ l1_b,
    const float* __restrict__ l2_w, const float* __restrict__ l2_b,
    const float* __restrict__ l3_w, const float* __restrict__ l3_b,
    const float* __restrict__ l4_w, const float* __restrict__ l4_b,
    const float* __restrict__ dec_wih, const float* __restrict__ dec_whh,
    const float* __restrict__ dec_bih, const float* __restrict__ dec_bhh,
    const float* __restrict__ fc_w, const float* __restrict__ fc_b,
    float* __restrict__ out)
{
  // Padded LDS weight tiles: stride 36 (2-way conflicts max on float4 reads), 20 for l4.
  __shared__ float s_l1w[32 * 36];
  __shared__ float s_l4w[32 * 20];
  __shared__ float s_dwih[96 * 36];
  __shared__ float s_dwhh[96 * 36];
  __shared__ float s_x[16][24][3];
  __shared__ float s_enc[16][24][16];

  const int tid = threadIdx.x;
  const int g = tid >> 4;
  const int j = tid & 15;
  const int b = blockIdx.x * 16 + g;
  const int j0 = j, j1 = j + 16;

  // ---- stage weights (padded) + this block's x ----
  for (int i = tid; i < 32 * 32; i += 256) s_l1w[(i >> 5) * 36 + (i & 31)] = l1_w[i];
  for (int i = tid; i < 32 * 19; i += 256) s_l4w[(i / 19) * 20 + (i % 19)] = l4_w[i];
  for (int i = tid; i < 96 * 32; i += 256) s_dwih[(i >> 5) * 36 + (i & 31)] = dec_wih[i];
  for (int i = tid; i < 96 * 32; i += 256) s_dwhh[(i >> 5) * 36 + (i & 31)] = dec_whh[i];
  {
    const int b0 = blockIdx.x * 16;
    for (int i = tid; i < 16 * 72; i += 256) {
      const int gg = i / 72, r = i - gg * 72;
      s_x[gg][r / 3][r % 3] = x[(b0 + gg) * 72 + r];
    }
  }
  __syncthreads();

  // ================= ENCODER =================
  const float A1c0 = attn1_w[j], A1c1 = attn1_w[16 + j], A1c2 = attn1_w[32 + j];
  const float a1b0 = attn1_b[0], a1b1 = attn1_b[1], a1b2 = attn1_b[2];
  float A2[9], A3[9];
#pragma unroll
  for (int i = 0; i < 9; ++i) { A2[i] = attn2_w[i]; A3[i] = attn3_w[i]; }
  const float a2b0 = attn2_b[0], a2b1 = attn2_b[1], a2b2 = attn2_b[2];
  const float a3b0 = attn3_b[0], a3b1 = attn3_b[1], a3b2 = attn3_b[2];
  float WI[3][3];
#pragma unroll
  for (int c = 0; c < 3; ++c)
#pragma unroll
    for (int i = 0; i < 3; ++i) WI[c][i] = enc_wih[(c * 16 + j) * 3 + i];
  const float BI0 = enc_bih[j], BI1 = enc_bih[16 + j], BI2 = enc_bih[32 + j];
  float WHr[16], WHz[16], WHn[16];
#pragma unroll
  for (int k = 0; k < 16; ++k) {
    WHr[k] = enc_whh[j * 16 + k];
    WHz[k] = enc_whh[(16 + j) * 16 + k];
    WHn[k] = enc_whh[(32 + j) * 16 + k];
  }
  const float BH0 = enc_bhh[j], BH1 = enc_bhh[16 + j], BH2 = enc_bhh[32 + j];

  float h = h0_enc[b * 16 + j];

  for (int t = 0; t < NT; ++t) {
    const float xs0 = s_x[g][t][0], xs1 = s_x[g][t][1], xs2 = s_x[g][t][2];
    // input-attention
    const float w10 = dpp16_sum(h * A1c0) + a1b0;
    const float w11 = dpp16_sum(h * A1c1) + a1b1;
    const float w12 = dpp16_sum(h * A1c2) + a1b2;
    const float w20 = a2b0 + xs0 * A2[0] + xs1 * A2[1] + xs2 * A2[2];
    const float w21 = a2b1 + xs0 * A2[3] + xs1 * A2[4] + xs2 * A2[5];
    const float w22 = a2b2 + xs0 * A2[6] + xs1 * A2[7] + xs2 * A2[8];
    const float t0 = tanh_f(w10 + w20), t1 = tanh_f(w11 + w21), t2 = tanh_f(w12 + w22);
    const float v0 = a3b0 + t0 * A3[0] + t1 * A3[1] + t2 * A3[2];
    const float v1 = a3b1 + t0 * A3[3] + t1 * A3[4] + t2 * A3[5];
    const float v2 = a3b2 + t0 * A3[6] + t1 * A3[7] + t2 * A3[8];
    const float m = fmaxf(fmaxf(v0, v1), v2);
    const float e0 = __expf(v0 - m), e1 = __expf(v1 - m), e2 = __expf(v2 - m);
    const float rs = rcp_fast(e0 + e1 + e2);
    const float wx0 = xs0 * e0 * rs, wx1 = xs1 * e1 * rs, wx2 = xs2 * e2 * rs;
    // GRU cell
    const float gir = BI0 + wx0 * WI[0][0] + wx1 * WI[0][1] + wx2 * WI[0][2];
    const float giz = BI1 + wx0 * WI[1][0] + wx1 * WI[1][1] + wx2 * WI[1][2];
    const float gin = BI2 + wx0 * WI[2][0] + wx1 * WI[2][1] + wx2 * WI[2][2];
    float ghr = BH0, ghz = BH1, ghn = BH2;
#pragma unroll
    for (int k = 0; k < 16; ++k) {
      const float hk = __shfl(h, k, 16);
      ghr += hk * WHr[k]; ghz += hk * WHz[k]; ghn += hk * WHn[k];
    }
    const float r = sigmoid_f(gir + ghr);
    const float z = sigmoid_f(giz + ghz);
    const float n = tanh_f(gin + r * ghn);
    h = (1.f - z) * n + z * h;
    s_enc[g][t][j] = h;
  }

  __syncthreads();

  // ================= DECODER =================
  const float l1b0 = l1_b[j0], l1b1 = l1_b[j1];
  const float l2b0 = l2_b[j0], l2b1 = l2_b[j1];
  const float l3w0 = l3_w[j0], l3w1 = l3_w[j1];
  const float l4b0 = l4_b[j0], l4b1 = l4_b[j1];
  const float X40 = l4_w[j0 * 19 + 16], X41 = l4_w[j0 * 19 + 17], X42 = l4_w[j0 * 19 + 18];
  const float X43 = l4_w[j1 * 19 + 16], X44 = l4_w[j1 * 19 + 17], X45 = l4_w[j1 * 19 + 18];
  const float DIr0 = dec_bih[j0], DIz0 = dec_bih[32 + j0], DIn0 = dec_bih[64 + j0];
  const float DIr1 = dec_bih[j1], DIz1 = dec_bih[32 + j1], DIn1 = dec_bih[64 + j1];
  const float DHr0 = dec_bhh[j0], DHz0 = dec_bhh[32 + j0], DHn0 = dec_bhh[64 + j0];
  const float DHr1 = dec_bhh[j1], DHz1 = dec_bhh[32 + j1], DHn1 = dec_bhh[64 + j1];

  float enc_reg[NT];
#pragma unroll
  for (int t = 0; t < NT; ++t) enc_reg[t] = s_enc[g][t][j];

  // loop-invariant w2d = enc @ l2^T + b  (kept in registers, 2 dims per lane)
  float w2d0[NT], w2d1[NT];
  {
    float L2a[16], L2b[16];
#pragma unroll
    for (int k = 0; k < 16; ++k) { L2a[k] = l2_w[j0 * 16 + k]; L2b[k] = l2_w[j1 * 16 + k]; }
#pragma unroll
    for (int t = 0; t < NT; ++t) {
      float a0 = l2b0, a1 = l2b1;
#pragma unroll
      for (int k = 0; k < 16; ++k) {
        const float ek = s_enc[g][t][k];  // broadcast read within group
        a0 += ek * L2a[k]; a1 += ek * L2b[k];
      }
      w2d0[t] = a0; w2d1[t] = a1;
    }
  }

  float hd0 = h0_dec[b * 32 + j0], hd1 = h0_dec[b * 32 + j1];

  for (int t = 0; t < NT; ++t) {
    const float xs0 = s_x[g][t][0], xs1 = s_x[g][t][1], xs2 = s_x[g][t][2];

    // --- w1 = l1(hd) ---
    float w10 = l1b0, w11 = l1b1;
#pragma unroll
    for (int kk = 0; kk < 4; ++kk) {
      const float4 wA = *(const float4*)&s_l1w[j0 * 36 + 4 * kk];
      const float4 wB = *(const float4*)&s_l1w[j1 * 36 + 4 * kk];
      const float b0 = __shfl(hd0, 4 * kk + 0, 16);
      const float b1 = __shfl(hd0, 4 * kk + 1, 16);
      const float b2 = __shfl(hd0, 4 * kk + 2, 16);
      const float b3 = __shfl(hd0, 4 * kk + 3, 16);
      w10 += b0 * wA.x + b1 * wA.y + b2 * wA.z + b3 * wA.w;
      w11 += b0 * wB.x + b1 * wB.y + b2 * wB.z + b3 * wB.w;
    }
#pragma unroll
    for (int kk = 0; kk < 4; ++kk) {
      const float4 wA = *(const float4*)&s_l1w[j0 * 36 + 16 + 4 * kk];
      const float4 wB = *(const float4*)&s_l1w[j1 * 36 + 16 + 4 * kk];
      const float b0 = __shfl(hd1, 4 * kk + 0, 16);
      const float b1 = __shfl(hd1, 4 * kk + 1, 16);
      const float b2 = __shfl(hd1, 4 * kk + 2, 16);
      const float b3 = __shfl(hd1, 4 * kk + 3, 16);
      w10 += b0 * wA.x + b1 * wA.y + b2 * wA.z + b3 * wA.w;
      w11 += b0 * wB.x + b1 * wB.y + b2 * wB.z + b3 * wB.w;
    }

    // --- temporal attention scores + softmax (bias dropped: shift-invariant) ---
    float a_[NT];
    float amax = -3.0e38f;
#pragma unroll
    for (int tp = 0; tp < NT; ++tp) {
      float s = l3w0 * tanh_f(w10 + w2d0[tp]) + l3w1 * tanh_f(w11 + w2d1[tp]);
      s = dpp16_sum(s);
      a_[tp] = s;
      amax = fmaxf(amax, s);
    }
    float esum = 0.f;
#pragma unroll
    for (int tp = 0; tp < NT; ++tp) { const float e = __expf(a_[tp] - amax); a_[tp] = e; esum += e; }
    const float rs = rcp_fast(esum);
    float wc = 0.f;
#pragma unroll
    for (int tp = 0; tp < NT; ++tp) wc += a_[tp] * enc_reg[tp];
    wc *= rs;  // context dim j on lane j

    // --- y0 = l4(cat(wc, x_s)) ---
    float y00 = l4b0 + xs0 * X40 + xs1 * X41 + xs2 * X42;
    float y01 = l4b1 + xs0 * X43 + xs1 * X44 + xs2 * X45;
#pragma unroll
    for (int kk = 0; kk < 4; ++kk) {
      const float4 wA = *(const float4*)&s_l4w[j0 * 20 + 4 * kk];
      const float4 wB = *(const float4*)&s_l4w[j1 * 20 + 4 * kk];
      const float c0 = __shfl(wc, 4 * kk + 0, 16);
      const float c1 = __shfl(wc, 4 * kk + 1, 16);
      const float c2 = __shfl(wc, 4 * kk + 2, 16);
      const float c3 = __shfl(wc, 4 * kk + 3, 16);
      y00 += c0 * wA.x + c1 * wA.y + c2 * wA.z + c3 * wA.w;
      y01 += c0 * wB.x + c1 * wB.y + c2 * wB.z + c3 * wB.w;
    }

    // --- GRU gates: gi = dec_wih @ y0 ---
    float gr0 = DIr0, gz0 = DIz0, gn0 = DIn0, gr1 = DIr1, gz1 = DIz1, gn1 = DIn1;
#pragma unroll
    for (int kk = 0; kk < 4; ++kk) {
      const float b0 = __shfl(y00, 4 * kk + 0, 16);
      const float b1 = __shfl(y00, 4 * kk + 1, 16);
      const float b2 = __shfl(y00, 4 * kk + 2, 16);
      const float b3 = __shfl(y00, 4 * kk + 3, 16);
      GATE6(s_dwih, b0, b1, b2, b3, 4 * kk);
    }
#pragma unroll
    for (int kk = 0; kk < 4; ++kk) {
      const float b0 = __shfl(y01, 4 * kk + 0, 16);
      const float b1 = __shfl(y01, 4 * kk + 1, 16);
      const float b2 = __shfl(y01, 4 * kk + 2, 16);
      const float b3 = __shfl(y01, 4 * kk + 3, 16);
      GATE6(s_dwih, b0, b1, b2, b3, 16 + 4 * kk);
    }
    const float ir0 = gr0, iz0 = gz0, in0 = gn0, ir1 = gr1, iz1 = gz1, in1 = gn1;

    // --- gh = dec_whh @ hd ---
    gr0 = DHr0; gz0 = DHz0; gn0 = DHn0; gr1 = DHr1; gz1 = DHz1; gn1 = DHn1;
#pragma unroll
    for (int kk = 0; kk < 4; ++kk) {
      const float b0 = __shfl(hd0, 4 * kk + 0, 16);
      const float b1 = __shfl(hd0, 4 * kk + 1, 16);
      const float b2 = __shfl(hd0, 4 * kk + 2, 16);
      const float b3 = __shfl(hd0, 4 * kk + 3, 16);
      GATE6(s_dwhh, b0, b1, b2, b3, 4 * kk);
    }
#pragma unroll
    for (int kk = 0; kk < 4; ++kk) {
      const float b0 = __shfl(hd1, 4 * kk + 0, 16);
      const float b1 = __shfl(hd1, 4 * kk + 1, 16);
      const float b2 = __shfl(hd1, 4 * kk + 2, 16);
      const float b3 = __shfl(hd1, 4 * kk + 3, 16);
      GATE6(s_dwhh, b0, b1, b2, b3, 16 + 4 * kk);
    }

    const float r0 = sigmoid_f(ir0 + gr0), z0 = sigmoid_f(iz0 + gz0);
    const float n0 = tanh_f(in0 + r0 * gn0);
    const float r1 = sigmoid_f(ir1 + gr1), z1 = sigmoid_f(iz1 + gz1);
    const float n1 = tanh_f(in1 + r1 * gn1);
    hd0 = (1.f - z0) * n0 + z0 * hd0;
    hd1 = (1.f - z1) * n1 + z1 * hd1;
  }

  // ---- final fc ----
  const float fw00 = fc_w[j0], fw01 = fc_w[j1];
  const float fw10 = fc_w[32 + j0], fw11 = fc_w[32 + j1];
  const float fw20 = fc_w[64 + j0], fw21 = fc_w[64 + j1];
  const float p0 = dpp16_sum(hd0 * fw00 + hd1 * fw01) + fc_b[0];
  const float p1 = dpp16_sum(hd0 * fw10 + hd1 * fw11) + fc_b[1];
  const float p2 = dpp16_sum(hd0 * fw20 + hd1 * fw21) + fc_b[2];
  if (j == 0) {
    out[b * 3 + 0] = p0;
    out[b * 3 + 1] = p1;
    out[b * 3 + 2] = p2;
  }
}

extern "C" void kernel_launch(void* const* d_in, const int* in_sizes, int n_in,
                              void* d_out, int out_size, void* d_ws, size_t ws_size,
                              hipStream_t stream) {
  const float* p[27];
  for (int i = 0; i < 27; ++i) p[i] = (const float*)d_in[i];
  darnn_kernel<<<NB / 16, 256, 0, stream>>>(
      p[0], p[1], p[2], p[3], p[4], p[5], p[6], p[7], p[8],
      p[9], p[10], p[11], p[12], p[13], p[14], p[15], p[16], p[17], p[18],
      p[19], p[20], p[21], p[22], p[23], p[24], p[25], p[26],
      (float*)d_out);
}

// Round 2
// 255.519 us; speedup vs baseline: 7.1708x; 7.1708x over previous
//
#include <hip/hip_runtime.h>

#define NB 8192
#define NT 24

__device__ __forceinline__ float rcp_fast(float x) { return __builtin_amdgcn_rcpf(x); }
__device__ __forceinline__ float sigmoid_f(float x) { return rcp_fast(1.f + __expf(-x)); }
__device__ __forceinline__ float tanh_f(float x) { return 1.f - 2.f * rcp_fast(1.f + __expf(2.f * x)); }
// same-wave LDS write->read ordering fence (lanes within a 16-lane group share a wave)
__device__ __forceinline__ void lds_fence() { asm volatile("s_waitcnt lgkmcnt(0)" ::: "memory"); }

// Full sum across the 16 contiguous lanes of a group (groups aligned to 16).
__device__ __forceinline__ float dpp16_sum(float x) {
  int v;
  v = __builtin_amdgcn_update_dpp(0, __float_as_int(x), 0xB1, 0xF, 0xF, true);  // quad_perm(1,0,3,2)
  x += __int_as_float(v);
  v = __builtin_amdgcn_update_dpp(0, __float_as_int(x), 0x4E, 0xF, 0xF, true);  // quad_perm(2,3,0,1)
  x += __int_as_float(v);
  v = __builtin_amdgcn_update_dpp(0, __float_as_int(x), 0x141, 0xF, 0xF, true); // ROW_HALF_MIRROR
  x += __int_as_float(v);
  v = __builtin_amdgcn_update_dpp(0, __float_as_int(x), 0x140, 0xF, 0xF, true); // ROW_MIRROR
  x += __int_as_float(v);
  return x;
}

// 6 gate rows (r,z,n for j0,j1) x 4 cols against padded [96][36] LDS matrix,
// broadcast quad BQ holds the 4 input-vector elements for cols COFF..COFF+3.
#define GATE6(WS, BQ, COFF)                                          \
  do {                                                               \
    const float4 wr0 = *(const float4*)&WS[(j0) * 36 + (COFF)];      \
    const float4 wz0 = *(const float4*)&WS[(32 + j0) * 36 + (COFF)]; \
    const float4 wn0 = *(const float4*)&WS[(64 + j0) * 36 + (COFF)]; \
    const float4 wr1 = *(const float4*)&WS[(j1) * 36 + (COFF)];      \
    const float4 wz1 = *(const float4*)&WS[(32 + j1) * 36 + (COFF)]; \
    const float4 wn1 = *(const float4*)&WS[(64 + j1) * 36 + (COFF)]; \
    gr0 += BQ.x * wr0.x + BQ.y * wr0.y + BQ.z * wr0.z + BQ.w * wr0.w; \
    gz0 += BQ.x * wz0.x + BQ.y * wz0.y + BQ.z * wz0.z + BQ.w * wz0.w; \
    gn0 += BQ.x * wn0.x + BQ.y * wn0.y + BQ.z * wn0.z + BQ.w * wn0.w; \
    gr1 += BQ.x * wr1.x + BQ.y * wr1.y + BQ.z * wr1.z + BQ.w * wr1.w; \
    gz1 += BQ.x * wz1.x + BQ.y * wz1.y + BQ.z * wz1.z + BQ.w * wz1.w; \
    gn1 += BQ.x * wn1.x + BQ.y * wn1.y + BQ.z * wn1.z + BQ.w * wn1.w; \
  } while (0)

__global__ __launch_bounds__(256) void darnn_kernel(
    const float* __restrict__ x, const float* __restrict__ h0_enc, const float* __restrict__ h0_dec,
    const float* __restrict__ attn1_w, const float* __restrict__ attn1_b,
    const float* __restrict__ attn2_w, const float* __restrict__ attn2_b,
    const float* __restrict__ attn3_w, const float* __restrict__ attn3_b,
    const float* __restrict__ enc_wih, const float* __restrict__ enc_whh,
    const float* __restrict__ enc_bih, const float* __restrict__ enc_bhh,
    const float* __restrict__ l1_w, const float* __restrict__ l1_b,
    const float* __restrict__ l2_w, const float* __restrict__ l2_b,
    const float* __restrict__ l3_w, const float* __restrict__ l3_b,
    const float* __restrict__ l4_w, const float* __restrict__ l4_b,
    const float* __restrict__ dec_wih, const float* __restrict__ dec_whh,
    const float* __restrict__ dec_bih, const float* __restrict__ dec_bhh,
    const float* __restrict__ fc_w, const float* __restrict__ fc_b,
    float* __restrict__ out)
{
  __shared__ float s_l1w[32 * 36];   // stride 36: 16B-aligned rows, <=2-way conflicts
  __shared__ float s_l4w[32 * 20];   // only cols 0..15 (wc part); x-cols live in regs
  __shared__ float s_dwih[96 * 36];
  __shared__ float s_dwhh[96 * 36];
  __shared__ float s_enc[16][24][16];
  __shared__ float s_bc[16][36];     // per-group broadcast buffer (h / hd / wc / y0)

  const int tid = threadIdx.x;
  const int g = tid >> 4;
  const int jj = tid & 15;
  const int b = blockIdx.x * 16 + g;
  const int j0 = jj, j1 = jj + 16;
  const float* __restrict__ xg = x + b * (NT * 3);

  for (int i = tid; i < 32 * 32; i += 256) s_l1w[(i >> 5) * 36 + (i & 31)] = l1_w[i];
  for (int i = tid; i < 32 * 16; i += 256) s_l4w[(i >> 4) * 20 + (i & 15)] = l4_w[(i >> 4) * 19 + (i & 15)];
  for (int i = tid; i < 96 * 32; i += 256) s_dwih[(i >> 5) * 36 + (i & 31)] = dec_wih[i];
  for (int i = tid; i < 96 * 32; i += 256) s_dwhh[(i >> 5) * 36 + (i & 31)] = dec_whh[i];
  __syncthreads();

  // ================= ENCODER =================
  const float A1c0 = attn1_w[jj], A1c1 = attn1_w[16 + jj], A1c2 = attn1_w[32 + jj];
  const float a1b0 = attn1_b[0], a1b1 = attn1_b[1], a1b2 = attn1_b[2];
  float A2[9], A3[9];
#pragma unroll
  for (int i = 0; i < 9; ++i) { A2[i] = attn2_w[i]; A3[i] = attn3_w[i]; }
  const float a2b0 = attn2_b[0], a2b1 = attn2_b[1], a2b2 = attn2_b[2];
  const float a3b0 = attn3_b[0], a3b1 = attn3_b[1], a3b2 = attn3_b[2];
  float WI[3][3];
#pragma unroll
  for (int c = 0; c < 3; ++c)
#pragma unroll
    for (int i = 0; i < 3; ++i) WI[c][i] = enc_wih[(c * 16 + jj) * 3 + i];
  const float BI0 = enc_bih[jj], BI1 = enc_bih[16 + jj], BI2 = enc_bih[32 + jj];
  float WHr[16], WHz[16], WHn[16];
#pragma unroll
  for (int k = 0; k < 16; ++k) {
    WHr[k] = enc_whh[jj * 16 + k];
    WHz[k] = enc_whh[(16 + jj) * 16 + k];
    WHn[k] = enc_whh[(32 + jj) * 16 + k];
  }
  const float BH0 = enc_bhh[jj], BH1 = enc_bhh[16 + jj], BH2 = enc_bhh[32 + jj];

  float h = h0_enc[b * 16 + jj];
  float xs0 = xg[0], xs1 = xg[1], xs2 = xg[2];

  for (int t = 0; t < NT; ++t) {
    float nx0 = 0.f, nx1 = 0.f, nx2 = 0.f;
    if (t + 1 < NT) { nx0 = xg[(t + 1) * 3 + 0]; nx1 = xg[(t + 1) * 3 + 1]; nx2 = xg[(t + 1) * 3 + 2]; }

    s_bc[g][jj] = h;
    lds_fence();

    // input-attention
    const float w10 = dpp16_sum(h * A1c0) + a1b0;
    const float w11 = dpp16_sum(h * A1c1) + a1b1;
    const float w12 = dpp16_sum(h * A1c2) + a1b2;
    const float w20 = a2b0 + xs0 * A2[0] + xs1 * A2[1] + xs2 * A2[2];
    const float w21 = a2b1 + xs0 * A2[3] + xs1 * A2[4] + xs2 * A2[5];
    const float w22 = a2b2 + xs0 * A2[6] + xs1 * A2[7] + xs2 * A2[8];
    const float t0 = tanh_f(w10 + w20), t1 = tanh_f(w11 + w21), t2 = tanh_f(w12 + w22);
    const float v0 = a3b0 + t0 * A3[0] + t1 * A3[1] + t2 * A3[2];
    const float v1 = a3b1 + t0 * A3[3] + t1 * A3[4] + t2 * A3[5];
    const float v2 = a3b2 + t0 * A3[6] + t1 * A3[7] + t2 * A3[8];
    const float m = fmaxf(fmaxf(v0, v1), v2);
    const float e0 = __expf(v0 - m), e1 = __expf(v1 - m), e2 = __expf(v2 - m);
    const float rs = rcp_fast(e0 + e1 + e2);
    const float wx0 = xs0 * e0 * rs, wx1 = xs1 * e1 * rs, wx2 = xs2 * e2 * rs;

    // GRU cell
    const float gir = BI0 + wx0 * WI[0][0] + wx1 * WI[0][1] + wx2 * WI[0][2];
    const float giz = BI1 + wx0 * WI[1][0] + wx1 * WI[1][1] + wx2 * WI[1][2];
    const float gin = BI2 + wx0 * WI[2][0] + wx1 * WI[2][1] + wx2 * WI[2][2];
    float ghr = BH0, ghz = BH1, ghn = BH2;
#pragma unroll
    for (int kk = 0; kk < 4; ++kk) {
      const float4 hq = *(const float4*)&s_bc[g][4 * kk];
      ghr += hq.x * WHr[4 * kk] + hq.y * WHr[4 * kk + 1] + hq.z * WHr[4 * kk + 2] + hq.w * WHr[4 * kk + 3];
      ghz += hq.x * WHz[4 * kk] + hq.y * WHz[4 * kk + 1] + hq.z * WHz[4 * kk + 2] + hq.w * WHz[4 * kk + 3];
      ghn += hq.x * WHn[4 * kk] + hq.y * WHn[4 * kk + 1] + hq.z * WHn[4 * kk + 2] + hq.w * WHn[4 * kk + 3];
    }
    const float r = sigmoid_f(gir + ghr);
    const float z = sigmoid_f(giz + ghz);
    const float n = tanh_f(gin + r * ghn);
    h = (1.f - z) * n + z * h;
    s_enc[g][t][jj] = h;
    xs0 = nx0; xs1 = nx1; xs2 = nx2;
  }
  lds_fence();  // group-local: decoder reads s_enc written by own group's lanes (same wave)

  // ================= DECODER =================
  const float l1b0 = l1_b[j0], l1b1 = l1_b[j1];
  const float l2b0 = l2_b[j0], l2b1 = l2_b[j1];
  const float l3w0 = l3_w[j0], l3w1 = l3_w[j1];
  const float l4b0 = l4_b[j0], l4b1 = l4_b[j1];
  const float X40 = l4_w[j0 * 19 + 16], X41 = l4_w[j0 * 19 + 17], X42 = l4_w[j0 * 19 + 18];
  const float X43 = l4_w[j1 * 19 + 16], X44 = l4_w[j1 * 19 + 17], X45 = l4_w[j1 * 19 + 18];
  const float DIr0 = dec_bih[j0], DIz0 = dec_bih[32 + j0], DIn0 = dec_bih[64 + j0];
  const float DIr1 = dec_bih[j1], DIz1 = dec_bih[32 + j1], DIn1 = dec_bih[64 + j1];
  const float DHr0 = dec_bhh[j0], DHz0 = dec_bhh[32 + j0], DHn0 = dec_bhh[64 + j0];
  const float DHr1 = dec_bhh[j1], DHz1 = dec_bhh[32 + j1], DHn1 = dec_bhh[64 + j1];

  float enc_reg[NT];
#pragma unroll
  for (int t = 0; t < NT; ++t) enc_reg[t] = s_enc[g][t][jj];

  // loop-invariant w2d = enc @ l2^T + b (2 dims per lane, registers)
  float w2d0[NT], w2d1[NT];
  {
    float L2a[16], L2b[16];
#pragma unroll
    for (int k = 0; k < 16; ++k) { L2a[k] = l2_w[j0 * 16 + k]; L2b[k] = l2_w[j1 * 16 + k]; }
#pragma unroll
    for (int t = 0; t < NT; ++t) {
      float a0 = l2b0, a1 = l2b1;
#pragma unroll
      for (int k4 = 0; k4 < 4; ++k4) {
        const float4 e = *(const float4*)&s_enc[g][t][4 * k4];
        a0 += e.x * L2a[4 * k4] + e.y * L2a[4 * k4 + 1] + e.z * L2a[4 * k4 + 2] + e.w * L2a[4 * k4 + 3];
        a1 += e.x * L2b[4 * k4] + e.y * L2b[4 * k4 + 1] + e.z * L2b[4 * k4 + 2] + e.w * L2b[4 * k4 + 3];
      }
      w2d0[t] = a0; w2d1[t] = a1;
    }
  }

  float hd0 = h0_dec[b * 32 + j0], hd1 = h0_dec[b * 32 + j1];
  xs0 = xg[0]; xs1 = xg[1]; xs2 = xg[2];

  for (int t = 0; t < NT; ++t) {
    float nx0 = 0.f, nx1 = 0.f, nx2 = 0.f;
    if (t + 1 < NT) { nx0 = xg[(t + 1) * 3 + 0]; nx1 = xg[(t + 1) * 3 + 1]; nx2 = xg[(t + 1) * 3 + 2]; }

    // broadcast hd to the group
    s_bc[g][jj] = hd0;
    s_bc[g][16 + jj] = hd1;
    lds_fence();

    // --- w1 = l1(hd) ---
    float w10 = l1b0, w11 = l1b1;
#pragma unroll
    for (int kk = 0; kk < 8; ++kk) {
      const float4 hq = *(const float4*)&s_bc[g][4 * kk];
      const float4 wA = *(const float4*)&s_l1w[j0 * 36 + 4 * kk];
      const float4 wB = *(const float4*)&s_l1w[j1 * 36 + 4 * kk];
      w10 += hq.x * wA.x + hq.y * wA.y + hq.z * wA.z + hq.w * wA.w;
      w11 += hq.x * wB.x + hq.y * wB.y + hq.z * wB.z + hq.w * wB.w;
    }

    // --- gh = dec_whh @ hd (while hd is still in s_bc) ---
    float gr0 = DHr0, gz0 = DHz0, gn0 = DHn0, gr1 = DHr1, gz1 = DHz1, gn1 = DHn1;
#pragma unroll
    for (int kk = 0; kk < 8; ++kk) {
      const float4 hq = *(const float4*)&s_bc[g][4 * kk];
      GATE6(s_dwhh, hq, 4 * kk);
    }
    const float hr0 = gr0, hz0 = gz0, hn0 = gn0, hr1 = gr1, hz1 = gz1, hn1 = gn1;

    // --- temporal attention: online softmax + context, no score array ---
    float m = -1.0e30f, ssum = 0.f, wc = 0.f;
#pragma unroll
    for (int tp = 0; tp < NT; ++tp) {
      float sc = l3w0 * tanh_f(w10 + w2d0[tp]) + l3w1 * tanh_f(w11 + w2d1[tp]);
      sc = dpp16_sum(sc);
      const float mn = fmaxf(m, sc);
      const float corr = __expf(m - mn);
      const float p = __expf(sc - mn);
      ssum = ssum * corr + p;
      wc = wc * corr + p * enc_reg[tp];
      m = mn;
    }
    wc *= rcp_fast(ssum);

    // --- y0 = l4(cat(wc, x_s)) ---
    s_bc[g][jj] = wc;  // in-order LDS: prior reads of s_bc complete first (same wave)
    lds_fence();
    float y00 = l4b0 + xs0 * X40 + xs1 * X41 + xs2 * X42;
    float y01 = l4b1 + xs0 * X43 + xs1 * X44 + xs2 * X45;
#pragma unroll
    for (int kk = 0; kk < 4; ++kk) {
      const float4 cq = *(const float4*)&s_bc[g][4 * kk];
      const float4 wA = *(const float4*)&s_l4w[j0 * 20 + 4 * kk];
      const float4 wB = *(const float4*)&s_l4w[j1 * 20 + 4 * kk];
      y00 += cq.x * wA.x + cq.y * wA.y + cq.z * wA.z + cq.w * wA.w;
      y01 += cq.x * wB.x + cq.y * wB.y + cq.z * wB.z + cq.w * wB.w;
    }

    // --- gi = dec_wih @ y0 ---
    s_bc[g][jj] = y00;
    s_bc[g][16 + jj] = y01;
    lds_fence();
    gr0 = DIr0; gz0 = DIz0; gn0 = DIn0; gr1 = DIr1; gz1 = DIz1; gn1 = DIn1;
#pragma unroll
    for (int kk = 0; kk < 8; ++kk) {
      const float4 yq = *(const float4*)&s_bc[g][4 * kk];
      GATE6(s_dwih, yq, 4 * kk);
    }

    const float r0 = sigmoid_f(gr0 + hr0), z0 = sigmoid_f(gz0 + hz0);
    const float n0 = tanh_f(gn0 + r0 * hn0);
    const float r1 = sigmoid_f(gr1 + hr1), z1 = sigmoid_f(gz1 + hz1);
    const float n1 = tanh_f(gn1 + r1 * hn1);
    hd0 = (1.f - z0) * n0 + z0 * hd0;
    hd1 = (1.f - z1) * n1 + z1 * hd1;
    xs0 = nx0; xs1 = nx1; xs2 = nx2;
  }

  // ---- final fc ----
  const float fw00 = fc_w[j0], fw01 = fc_w[j1];
  const float fw10 = fc_w[32 + j0], fw11 = fc_w[32 + j1];
  const float fw20 = fc_w[64 + j0], fw21 = fc_w[64 + j1];
  const float p0 = dpp16_sum(hd0 * fw00 + hd1 * fw01) + fc_b[0];
  const float p1 = dpp16_sum(hd0 * fw10 + hd1 * fw11) + fc_b[1];
  const float p2 = dpp16_sum(hd0 * fw20 + hd1 * fw21) + fc_b[2];
  if (jj == 0) {
    out[b * 3 + 0] = p0;
    out[b * 3 + 1] = p1;
    out[b * 3 + 2] = p2;
  }
}

extern "C" void kernel_launch(void* const* d_in, const int* in_sizes, int n_in,
                              void* d_out, int out_size, void* d_ws, size_t ws_size,
                              hipStream_t stream) {
  const float* p[27];
  for (int i = 0; i < 27; ++i) p[i] = (const float*)d_in[i];
  darnn_kernel<<<NB / 16, 256, 0, stream>>>(
      p[0], p[1], p[2], p[3], p[4], p[5], p[6], p[7], p[8],
      p[9], p[10], p[11], p[12], p[13], p[14], p[15], p[16], p[17], p[18],
      p[19], p[20], p[21], p[22], p[23], p[24], p[25], p[26],
      (float*)d_out);
}

// Round 3
// 146.146 us; speedup vs baseline: 12.5373x; 1.7484x over previous
//
#include <hip/hip_runtime.h>

#define NB 8192
#define NT 24

typedef float v2f __attribute__((ext_vector_type(2)));

__device__ __forceinline__ float rcp_fast(float x) { return __builtin_amdgcn_rcpf(x); }
__device__ __forceinline__ float sigmoid_f(float x) { return rcp_fast(1.f + __expf(-x)); }
__device__ __forceinline__ float tanh_f(float x) { return 1.f - 2.f * rcp_fast(1.f + __expf(2.f * x)); }
// same-wave LDS write->read ordering (16-lane groups live inside one 64-lane wave)
__device__ __forceinline__ void lds_fence() { asm volatile("s_waitcnt lgkmcnt(0)" ::: "memory"); }
__device__ __forceinline__ v2f v2(float a, float b) { v2f r; r.x = a; r.y = b; return r; }
__device__ __forceinline__ v2f v2s(float a) { v2f r; r.x = a; r.y = a; return r; }
__device__ __forceinline__ v2f v2fma(v2f a, v2f b, v2f c) { return __builtin_elementwise_fma(a, b, c); }

// Full sum across the 16 contiguous lanes of a group (groups aligned to 16).
__device__ __forceinline__ float dpp16_sum(float x) {
  int v;
  v = __builtin_amdgcn_update_dpp(0, __float_as_int(x), 0xB1, 0xF, 0xF, true);  // quad_perm(1,0,3,2)
  x += __int_as_float(v);
  v = __builtin_amdgcn_update_dpp(0, __float_as_int(x), 0x4E, 0xF, 0xF, true);  // quad_perm(2,3,0,1)
  x += __int_as_float(v);
  v = __builtin_amdgcn_update_dpp(0, __float_as_int(x), 0x141, 0xF, 0xF, true); // ROW_HALF_MIRROR
  x += __int_as_float(v);
  v = __builtin_amdgcn_update_dpp(0, __float_as_int(x), 0x140, 0xF, 0xF, true); // ROW_MIRROR
  x += __int_as_float(v);
  return x;
}

// 3 packed gate accumulators (r,z,n as v2f over dims j0,j1), 4 input cols 4*kk..4*kk+3.
// Tile layout: float4 T[(q*16 + cp)*16 + jj] = {W[q*32+jj][2cp], W[q*32+16+jj][2cp],
//                                               W[q*32+jj][2cp+1], W[q*32+16+jj][2cp+1]}
#define GATE_PK(T, hq, kk, gr, gz, gn)                          \
  do {                                                          \
    const float4 a0 = T[(0 * 16 + 2 * (kk)) * 16 + jj];         \
    const float4 a1 = T[(0 * 16 + 2 * (kk) + 1) * 16 + jj];     \
    const float4 b0 = T[(1 * 16 + 2 * (kk)) * 16 + jj];         \
    const float4 b1 = T[(1 * 16 + 2 * (kk) + 1) * 16 + jj];     \
    const float4 c0 = T[(2 * 16 + 2 * (kk)) * 16 + jj];         \
    const float4 c1 = T[(2 * 16 + 2 * (kk) + 1) * 16 + jj];     \
    gr = v2fma(v2s(hq.x), v2(a0.x, a0.y), gr);                  \
    gr = v2fma(v2s(hq.y), v2(a0.z, a0.w), gr);                  \
    gr = v2fma(v2s(hq.z), v2(a1.x, a1.y), gr);                  \
    gr = v2fma(v2s(hq.w), v2(a1.z, a1.w), gr);                  \
    gz = v2fma(v2s(hq.x), v2(b0.x, b0.y), gz);                  \
    gz = v2fma(v2s(hq.y), v2(b0.z, b0.w), gz);                  \
    gz = v2fma(v2s(hq.z), v2(b1.x, b1.y), gz);                  \
    gz = v2fma(v2s(hq.w), v2(b1.z, b1.w), gz);                  \
    gn = v2fma(v2s(hq.x), v2(c0.x, c0.y), gn);                  \
    gn = v2fma(v2s(hq.y), v2(c0.z, c0.w), gn);                  \
    gn = v2fma(v2s(hq.z), v2(c1.x, c1.y), gn);                  \
    gn = v2fma(v2s(hq.w), v2(c1.z, c1.w), gn);                  \
  } while (0)

__global__ __launch_bounds__(256, 3) void darnn_kernel(
    const float* __restrict__ x, const float* __restrict__ h0_enc, const float* __restrict__ h0_dec,
    const float* __restrict__ attn1_w, const float* __restrict__ attn1_b,
    const float* __restrict__ attn2_w, const float* __restrict__ attn2_b,
    const float* __restrict__ attn3_w, const float* __restrict__ attn3_b,
    const float* __restrict__ enc_wih, const float* __restrict__ enc_whh,
    const float* __restrict__ enc_bih, const float* __restrict__ enc_bhh,
    const float* __restrict__ l1_w, const float* __restrict__ l1_b,
    const float* __restrict__ l2_w, const float* __restrict__ l2_b,
    const float* __restrict__ l3_w, const float* __restrict__ l3_b,
    const float* __restrict__ l4_w, const float* __restrict__ l4_b,
    const float* __restrict__ dec_wih, const float* __restrict__ dec_whh,
    const float* __restrict__ dec_bih, const float* __restrict__ dec_bhh,
    const float* __restrict__ fc_w, const float* __restrict__ fc_b,
    float* __restrict__ out)
{
  __shared__ float4 s_dwih4[768];  // 12 KB, pair-interleaved (see GATE_PK)
  __shared__ float4 s_dwhh4[768];  // 12 KB
  __shared__ float4 s_l1w4[256];   // 4 KB: [cp*16+j] = {l1[j][2cp], l1[j+16][2cp], l1[j][2cp+1], l1[j+16][2cp+1]}
  __shared__ float4 s_l4w4[128];   // 2 KB (wc cols 0..15 only)
  __shared__ float4 s_l2w4[128];   // 2 KB
  __shared__ float4 s_x4[16][24];  // 6 KB, {x0,x1,x2,pad} per (group,t)
  __shared__ float s_bc[16][36];   // per-group broadcast buffer

  const int tid = threadIdx.x;
  const int g = tid >> 4;
  const int jj = tid & 15;
  const int b = blockIdx.x * 16 + g;
  const int j0 = jj, j1 = jj + 16;

  // ---- stage packed weight tiles + x ----
  for (int i = tid; i < 768; i += 256) {
    const int q = i >> 8, cp = (i >> 4) & 15, j = i & 15;
    const int r0 = q * 32 + j, r1 = r0 + 16, c0 = 2 * cp;
    float4 f;
    f.x = dec_wih[r0 * 32 + c0]; f.y = dec_wih[r1 * 32 + c0];
    f.z = dec_wih[r0 * 32 + c0 + 1]; f.w = dec_wih[r1 * 32 + c0 + 1];
    s_dwih4[i] = f;
    f.x = dec_whh[r0 * 32 + c0]; f.y = dec_whh[r1 * 32 + c0];
    f.z = dec_whh[r0 * 32 + c0 + 1]; f.w = dec_whh[r1 * 32 + c0 + 1];
    s_dwhh4[i] = f;
  }
  {
    const int i = tid;  // exactly 256
    const int cp = i >> 4, j = i & 15, c0 = 2 * cp;
    float4 f;
    f.x = l1_w[j * 32 + c0]; f.y = l1_w[(j + 16) * 32 + c0];
    f.z = l1_w[j * 32 + c0 + 1]; f.w = l1_w[(j + 16) * 32 + c0 + 1];
    s_l1w4[i] = f;
  }
  if (tid < 128) {
    const int cp = tid >> 4, j = tid & 15, c0 = 2 * cp;
    float4 f;
    f.x = l4_w[j * 19 + c0]; f.y = l4_w[(j + 16) * 19 + c0];
    f.z = l4_w[j * 19 + c0 + 1]; f.w = l4_w[(j + 16) * 19 + c0 + 1];
    s_l4w4[tid] = f;
    float4 e;
    e.x = l2_w[j * 16 + c0]; e.y = l2_w[(j + 16) * 16 + c0];
    e.z = l2_w[j * 16 + c0 + 1]; e.w = l2_w[(j + 16) * 16 + c0 + 1];
    s_l2w4[tid] = e;
  }
  {
    const int b0 = blockIdx.x * 16;
    for (int i = tid; i < 16 * 24; i += 256) {
      const int gg = i / 24, tt = i - gg * 24;
      const float* src = x + (b0 + gg) * 72 + tt * 3;
      float4 f; f.x = src[0]; f.y = src[1]; f.z = src[2]; f.w = 0.f;
      s_x4[gg][tt] = f;
    }
  }
  __syncthreads();

  // ================= ENCODER (+ inline w2d) =================
  const float A1c0 = attn1_w[jj], A1c1 = attn1_w[16 + jj], A1c2 = attn1_w[32 + jj];
  const float a1b0 = attn1_b[0], a1b1 = attn1_b[1], a1b2 = attn1_b[2];
  float A2[9], A3[9];
#pragma unroll
  for (int i = 0; i < 9; ++i) { A2[i] = attn2_w[i]; A3[i] = attn3_w[i]; }
  const float a2b0 = attn2_b[0], a2b1 = attn2_b[1], a2b2 = attn2_b[2];
  const float a3b0 = attn3_b[0], a3b1 = attn3_b[1], a3b2 = attn3_b[2];
  float WI[3][3];
#pragma unroll
  for (int c = 0; c < 3; ++c)
#pragma unroll
    for (int i = 0; i < 3; ++i) WI[c][i] = enc_wih[(c * 16 + jj) * 3 + i];
  const float BI0 = enc_bih[jj], BI1 = enc_bih[16 + jj], BI2 = enc_bih[32 + jj];
  float WHr[16], WHz[16], WHn[16];
#pragma unroll
  for (int k = 0; k < 16; ++k) {
    WHr[k] = enc_whh[jj * 16 + k];
    WHz[k] = enc_whh[(16 + jj) * 16 + k];
    WHn[k] = enc_whh[(32 + jj) * 16 + k];
  }
  const float BH0 = enc_bhh[jj], BH1 = enc_bhh[16 + jj], BH2 = enc_bhh[32 + jj];
  const v2f l2bv = v2(l2_b[j0], l2_b[j1]);

  float h = h0_enc[b * 16 + jj];
  float enc_reg[NT];
  v2f w2dv[NT];

  s_bc[g][jj] = h;
  lds_fence();

#pragma unroll
  for (int t = 0; t < NT; ++t) {
    const float4 xq = s_x4[g][t];
    const float xs0 = xq.x, xs1 = xq.y, xs2 = xq.z;
    // input-attention (3 independent dpp16 chains)
    const float w10 = dpp16_sum(h * A1c0) + a1b0;
    const float w11 = dpp16_sum(h * A1c1) + a1b1;
    const float w12 = dpp16_sum(h * A1c2) + a1b2;
    const float w20 = a2b0 + xs0 * A2[0] + xs1 * A2[1] + xs2 * A2[2];
    const float w21 = a2b1 + xs0 * A2[3] + xs1 * A2[4] + xs2 * A2[5];
    const float w22 = a2b2 + xs0 * A2[6] + xs1 * A2[7] + xs2 * A2[8];
    const float t0 = tanh_f(w10 + w20), t1 = tanh_f(w11 + w21), t2 = tanh_f(w12 + w22);
    const float v0 = a3b0 + t0 * A3[0] + t1 * A3[1] + t2 * A3[2];
    const float v1 = a3b1 + t0 * A3[3] + t1 * A3[4] + t2 * A3[5];
    const float v2_ = a3b2 + t0 * A3[6] + t1 * A3[7] + t2 * A3[8];
    const float m = fmaxf(fmaxf(v0, v1), v2_);
    const float e0 = __expf(v0 - m), e1 = __expf(v1 - m), e2 = __expf(v2_ - m);
    const float rs = rcp_fast(e0 + e1 + e2);
    const float wx0 = xs0 * e0 * rs, wx1 = xs1 * e1 * rs, wx2 = xs2 * e2 * rs;
    // GRU cell
    const float gir = BI0 + wx0 * WI[0][0] + wx1 * WI[0][1] + wx2 * WI[0][2];
    const float giz = BI1 + wx0 * WI[1][0] + wx1 * WI[1][1] + wx2 * WI[1][2];
    const float gin = BI2 + wx0 * WI[2][0] + wx1 * WI[2][1] + wx2 * WI[2][2];
    float ghr = BH0, ghz = BH1, ghn = BH2;
#pragma unroll
    for (int kk = 0; kk < 4; ++kk) {
      const float4 hq = *(const float4*)&s_bc[g][4 * kk];
      ghr += hq.x * WHr[4 * kk] + hq.y * WHr[4 * kk + 1] + hq.z * WHr[4 * kk + 2] + hq.w * WHr[4 * kk + 3];
      ghz += hq.x * WHz[4 * kk] + hq.y * WHz[4 * kk + 1] + hq.z * WHz[4 * kk + 2] + hq.w * WHz[4 * kk + 3];
      ghn += hq.x * WHn[4 * kk] + hq.y * WHn[4 * kk + 1] + hq.z * WHn[4 * kk + 2] + hq.w * WHn[4 * kk + 3];
    }
    const float r = sigmoid_f(gir + ghr);
    const float z = sigmoid_f(giz + ghz);
    const float n = tanh_f(gin + r * ghn);
    h = (1.f - z) * n + z * h;
    enc_reg[t] = h;
    s_bc[g][jj] = h;
    lds_fence();
    // w2d[t] = l2(enc[t]) packed over (j0,j1)
    v2f w2t = l2bv;
#pragma unroll
    for (int kk = 0; kk < 4; ++kk) {
      const float4 hq = *(const float4*)&s_bc[g][4 * kk];
      const float4 f0 = s_l2w4[(2 * kk) * 16 + jj];
      const float4 f1 = s_l2w4[(2 * kk + 1) * 16 + jj];
      w2t = v2fma(v2s(hq.x), v2(f0.x, f0.y), w2t);
      w2t = v2fma(v2s(hq.y), v2(f0.z, f0.w), w2t);
      w2t = v2fma(v2s(hq.z), v2(f1.x, f1.y), w2t);
      w2t = v2fma(v2s(hq.w), v2(f1.z, f1.w), w2t);
    }
    w2dv[t] = w2t;
  }

  // ================= DECODER =================
  const v2f l1bv = v2(l1_b[j0], l1_b[j1]);
  const v2f l3v = v2(l3_w[j0], l3_w[j1]);
  const v2f l4bv = v2(l4_b[j0], l4_b[j1]);
  const v2f x4v0 = v2(l4_w[j0 * 19 + 16], l4_w[j1 * 19 + 16]);
  const v2f x4v1 = v2(l4_w[j0 * 19 + 17], l4_w[j1 * 19 + 17]);
  const v2f x4v2 = v2(l4_w[j0 * 19 + 18], l4_w[j1 * 19 + 18]);
  const v2f dirv = v2(dec_bih[j0], dec_bih[j1]);
  const v2f dizv = v2(dec_bih[32 + j0], dec_bih[32 + j1]);
  const v2f dinv = v2(dec_bih[64 + j0], dec_bih[64 + j1]);
  const v2f dhrv = v2(dec_bhh[j0], dec_bhh[j1]);
  const v2f dhzv = v2(dec_bhh[32 + j0], dec_bhh[32 + j1]);
  const v2f dhnv = v2(dec_bhh[64 + j0], dec_bhh[64 + j1]);

  float hd0 = h0_dec[b * 32 + j0], hd1 = h0_dec[b * 32 + j1];

  for (int t = 0; t < NT; ++t) {
    const float4 xq = s_x4[g][t];

    s_bc[g][jj] = hd0;
    s_bc[g][16 + jj] = hd1;
    lds_fence();

    // --- w1 = l1(hd) and gh = dec_whh @ hd (share the hd broadcast quads) ---
    v2f w1v = l1bv;
    v2f hrv = dhrv, hzv = dhzv, hnv = dhnv;
#pragma unroll
    for (int kk = 0; kk < 8; ++kk) {
      const float4 hq = *(const float4*)&s_bc[g][4 * kk];
      const float4 f0 = s_l1w4[(2 * kk) * 16 + jj];
      const float4 f1 = s_l1w4[(2 * kk + 1) * 16 + jj];
      w1v = v2fma(v2s(hq.x), v2(f0.x, f0.y), w1v);
      w1v = v2fma(v2s(hq.y), v2(f0.z, f0.w), w1v);
      w1v = v2fma(v2s(hq.z), v2(f1.x, f1.y), w1v);
      w1v = v2fma(v2s(hq.w), v2(f1.z, f1.w), w1v);
      GATE_PK(s_dwhh4, hq, kk, hrv, hzv, hnv);
    }

    // --- temporal attention: chunked online softmax (4 independent dpp16 chains/chunk) ---
    float m = -1.0e30f, ssum = 0.f, wc = 0.f;
#pragma unroll
    for (int ch = 0; ch < 6; ++ch) {
      float sv[4];
#pragma unroll
      for (int u = 0; u < 4; ++u) {
        const v2f av = w1v + w2dv[4 * ch + u];
        sv[u] = dpp16_sum(l3v.x * tanh_f(av.x) + l3v.y * tanh_f(av.y));
      }
      const float cm = fmaxf(fmaxf(sv[0], sv[1]), fmaxf(sv[2], sv[3]));
      const float mn = fmaxf(m, cm);
      const float corr = __expf(m - mn);
      const float p0 = __expf(sv[0] - mn), p1 = __expf(sv[1] - mn);
      const float p2 = __expf(sv[2] - mn), p3 = __expf(sv[3] - mn);
      ssum = ssum * corr + ((p0 + p1) + (p2 + p3));
      wc = wc * corr + ((p0 * enc_reg[4 * ch] + p1 * enc_reg[4 * ch + 1]) +
                        (p2 * enc_reg[4 * ch + 2] + p3 * enc_reg[4 * ch + 3]));
      m = mn;
    }
    wc *= rcp_fast(ssum);

    // --- y0 = l4(cat(wc, x_s)) ---
    s_bc[g][jj] = wc;  // same-wave in-order LDS: hd reads above already issued
    lds_fence();
    v2f y0v = l4bv;
    y0v = v2fma(v2s(xq.x), x4v0, y0v);
    y0v = v2fma(v2s(xq.y), x4v1, y0v);
    y0v = v2fma(v2s(xq.z), x4v2, y0v);
#pragma unroll
    for (int kk = 0; kk < 4; ++kk) {
      const float4 cq = *(const float4*)&s_bc[g][4 * kk];
      const float4 f0 = s_l4w4[(2 * kk) * 16 + jj];
      const float4 f1 = s_l4w4[(2 * kk + 1) * 16 + jj];
      y0v = v2fma(v2s(cq.x), v2(f0.x, f0.y), y0v);
      y0v = v2fma(v2s(cq.y), v2(f0.z, f0.w), y0v);
      y0v = v2fma(v2s(cq.z), v2(f1.x, f1.y), y0v);
      y0v = v2fma(v2s(cq.w), v2(f1.z, f1.w), y0v);
    }

    // --- gi = dec_wih @ y0 ---
    s_bc[g][jj] = y0v.x;
    s_bc[g][16 + jj] = y0v.y;
    lds_fence();
    v2f irv = dirv, izv = dizv, inv = dinv;
#pragma unroll
    for (int kk = 0; kk < 8; ++kk) {
      const float4 yq = *(const float4*)&s_bc[g][4 * kk];
      GATE_PK(s_dwih4, yq, kk, irv, izv, inv);
    }

    const float r0 = sigmoid_f(irv.x + hrv.x), r1 = sigmoid_f(irv.y + hrv.y);
    const float z0 = sigmoid_f(izv.x + hzv.x), z1 = sigmoid_f(izv.y + hzv.y);
    const float n0 = tanh_f(inv.x + r0 * hnv.x), n1 = tanh_f(inv.y + r1 * hnv.y);
    hd0 = (1.f - z0) * n0 + z0 * hd0;
    hd1 = (1.f - z1) * n1 + z1 * hd1;
  }

  // ---- final fc ----
  const float p0 = dpp16_sum(hd0 * fc_w[jj] + hd1 * fc_w[16 + jj]) + fc_b[0];
  const float p1 = dpp16_sum(hd0 * fc_w[32 + jj] + hd1 * fc_w[48 + jj]) + fc_b[1];
  const float p2 = dpp16_sum(hd0 * fc_w[64 + jj] + hd1 * fc_w[80 + jj]) + fc_b[2];
  if (jj == 0) {
    out[b * 3 + 0] = p0;
    out[b * 3 + 1] = p1;
    out[b * 3 + 2] = p2;
  }
}

extern "C" void kernel_launch(void* const* d_in, const int* in_sizes, int n_in,
                              void* d_out, int out_size, void* d_ws, size_t ws_size,
                              hipStream_t stream) {
  const float* p[27];
  for (int i = 0; i < 27; ++i) p[i] = (const float*)d_in[i];
  darnn_kernel<<<NB / 16, 256, 0, stream>>>(
      p[0], p[1], p[2], p[3], p[4], p[5], p[6], p[7], p[8],
      p[9], p[10], p[11], p[12], p[13], p[14], p[15], p[16], p[17], p[18],
      p[19], p[20], p[21], p[22], p[23], p[24], p[25], p[26],
      (float*)d_out);
}